// Round 3
// baseline (620.736 us; speedup 1.0000x reference)
//
#include <hip/hip_runtime.h>

// ---------------- problem constants ----------------
#define NN 50000
#define EE 800000
// HID=128, EDGE_DIM=16, HEADS=4, C=32

typedef unsigned short u16;

// ---------------- ws layout (4-byte element offsets), total ~64.3 MB ----------------
#define OFF_GAT  0u          // N*128 f32
#define OFF_XLB  6400000u    // N*128 bf16
#define OFF_XRB  9600000u    // N*128 bf16
#define OFF_SE   12800000u   // E int2 (CSR-ordered {src, eid})
#define OFF_CNT  14400000u   // N ints
#define OFF_OFS  14450000u   // N+1 ints
#define OFF_H    6400000u    // aliases XLB+XRB after k2
#define OFF_HB   12800000u   // aliases SE+CNT+OFS after k2
#define OFF_WLRT 16000000u
#define OFF_W1T  16016384u
#define OFF_W2T  16049152u

#define RMS_EPS 1.1920928955078125e-7f

typedef float f32x4v __attribute__((ext_vector_type(4)));
typedef short s16x8 __attribute__((ext_vector_type(8)));

__device__ __forceinline__ f32x4v mfma16(s16x8 a, s16x8 b, f32x4v c) {
  return __builtin_amdgcn_mfma_f32_16x16x32_bf16(a, b, c, 0, 0, 0);
}
__device__ __forceinline__ u16 f2b(float f) {
  unsigned int u = __float_as_uint(f);
  unsigned int r = (u + 0x7fffu + ((u >> 16) & 1u)) >> 16;
  return (u16)r;
}
__device__ __forceinline__ float b2f(u16 u) {
  union { float f; unsigned int i; } x; x.i = ((unsigned int)u) << 16; return x.f;
}
__device__ __forceinline__ s16x8 ld_bf16x8_f32(const float* __restrict__ p) {
  float4 v0 = *(const float4*)p;
  float4 v1 = *(const float4*)(p + 4);
  s16x8 r;
  r[0] = (short)f2b(v0.x); r[1] = (short)f2b(v0.y);
  r[2] = (short)f2b(v0.z); r[3] = (short)f2b(v0.w);
  r[4] = (short)f2b(v1.x); r[5] = (short)f2b(v1.y);
  r[6] = (short)f2b(v1.z); r[7] = (short)f2b(v1.w);
  return r;
}
__device__ __forceinline__ int readlane_i32(int v, int lane) {
  return __builtin_amdgcn_readlane(v, lane);
}
// tanh-form GELU via sigmoid
__device__ __forceinline__ float gelu_fast(float x) {
  float x2 = x * x;
  float y = x * fmaf(0.07135481283f, x2, 1.5957691216f);
  float e = __expf(-y);
  return x * __builtin_amdgcn_rcpf(1.0f + e);
}

// ---------------- fused prep ----------------
__global__ __launch_bounds__(256) void k_prep(const float* __restrict__ Wl, const float* __restrict__ Wr,
    const float* __restrict__ W1, const float* __restrict__ W2,
    int* __restrict__ cnt, u16* __restrict__ wlrt, u16* __restrict__ w1t, u16* __restrict__ w2t)
{
  int i = blockIdx.x * 256 + threadIdx.x;
  if (i < NN) cnt[i] = 0;
  if (i < 32768) {
    int n = i >> 7, k = i & 127;
    float v = (n < 128) ? Wl[k * 128 + n] : Wr[k * 128 + (n - 128)];
    wlrt[i] = f2b(v);
  }
  {
    int n = i >> 7, k = i & 127;
    w1t[i] = f2b(W1[k * 512 + n]);
  }
  {
    int n = i >> 9, k = i & 511;
    w2t[i] = f2b(W2[k * 128 + n]);
  }
}

// ---------------- CSR build ----------------
__global__ __launch_bounds__(256) void k_hist(const int* __restrict__ ei, int* __restrict__ cnt) {
  int e = blockIdx.x * 256 + threadIdx.x;
  if (e < EE) atomicAdd(&cnt[ei[EE + e]], 1);
}

__global__ __launch_bounds__(1024) void k_scan(const int* __restrict__ cnt,
    int* __restrict__ offs, int* __restrict__ pos)
{
  __shared__ int wsum[16];
  __shared__ int carry_s;
  int tid = threadIdx.x, lane = tid & 63, wv = tid >> 6;
  if (tid == 0) carry_s = 0;
  __syncthreads();
  for (int base = 0; base < NN; base += 1024) {
    int i = base + tid;
    int v = (i < NN) ? cnt[i] : 0;
    int x = v;
#pragma unroll
    for (int ofs = 1; ofs < 64; ofs <<= 1) {
      int y = __shfl_up(x, ofs);
      if (lane >= ofs) x += y;
    }
    if (lane == 63) wsum[wv] = x;
    __syncthreads();
    if (wv == 0) {
      int s = (lane < 16) ? wsum[lane] : 0;
#pragma unroll
      for (int ofs = 1; ofs < 16; ofs <<= 1) {
        int y = __shfl_up(s, ofs);
        if (lane >= ofs) s += y;
      }
      if (lane < 16) wsum[lane] = s;
    }
    __syncthreads();
    int wbase = (wv > 0) ? wsum[wv - 1] : 0;
    int incl = x + wbase + carry_s;
    if (i < NN) { offs[i + 1] = incl; pos[i] = incl - v; }
    if (base == 0 && tid == 0) offs[0] = 0;
    __syncthreads();
    if (tid == 1023) carry_s = incl;
    __syncthreads();
  }
}

__global__ __launch_bounds__(256) void k_permute(const int* __restrict__ ei,
    int* __restrict__ pos, int2* __restrict__ se)
{
  int e = blockIdx.x * 256 + threadIdx.x;
  if (e < EE) {
    int slot = atomicAdd(&pos[ei[EE + e]], 1);
    se[slot] = make_int2(ei[e], e);
  }
}

// ---------------- K1: [xl|xr] = x @ [Wl|Wr] + [bl|br] -> bf16 ----------------
__global__ __launch_bounds__(256) void k1_mfma(const float* __restrict__ x, const u16* __restrict__ wlrt,
    const float* __restrict__ bl, const float* __restrict__ br,
    u16* __restrict__ xlb, u16* __restrict__ xrb)
{
  int tid = threadIdx.x;
  int w = tid >> 6, lane = tid & 63;
  int quad = lane >> 4, l16 = lane & 15;
  int row0 = blockIdx.x * 32;
  int ko = quad * 8;
  f32x4v acc[2][4];
#pragma unroll
  for (int mt = 0; mt < 2; ++mt)
#pragma unroll
    for (int nt = 0; nt < 4; ++nt) acc[mt][nt] = (f32x4v){0.f, 0.f, 0.f, 0.f};
#pragma unroll
  for (int ks = 0; ks < 4; ++ks) {
    int k0 = ks * 32 + ko;
    s16x8 a[2];
#pragma unroll
    for (int mt = 0; mt < 2; ++mt) {
      int row = row0 + mt * 16 + l16; if (row >= NN) row = NN - 1;
      a[mt] = ld_bf16x8_f32(x + row * 128 + k0);
    }
#pragma unroll
    for (int nt = 0; nt < 4; ++nt) {
      int col = w * 64 + nt * 16 + l16;
      s16x8 b = *(const s16x8*)(wlrt + col * 128 + k0);
      acc[0][nt] = mfma16(a[0], b, acc[0][nt]);
      acc[1][nt] = mfma16(a[1], b, acc[1][nt]);
    }
  }
#pragma unroll
  for (int nt = 0; nt < 4; ++nt) {
    int col = w * 64 + nt * 16 + l16;
    bool isl = col < 128;
    float bias = isl ? bl[col] : br[col - 128];
    u16* dst = isl ? xlb : xrb;
    int cc = isl ? col : col - 128;
#pragma unroll
    for (int mt = 0; mt < 2; ++mt)
#pragma unroll
      for (int r = 0; r < 4; ++r) {
        int row = row0 + mt * 16 + quad * 4 + r;
        if (row < NN) dst[row * 128 + cc] = f2b(acc[mt][nt][r] + bias);
      }
  }
}

// ---------------- K2: register-resident MFMA edge projection + block softmax ----------------
// Orientation: ep = mfma(A=We^T-frag, B=ea-frag) -> C[ch][edge]:
//   lane l holds edge l&15, channels {16t + 4*quad + r}, t=0..7, r=0..3.
// Logits reduced cross-quad via 2-stage select-exchange so lane ends with
// logit[edge=l16, head=quad] (head matches the O-accum channel layout c0=2l).
// No LDS at all; ep never leaves registers.
__global__ __launch_bounds__(256) void k2_attn(
    const int* __restrict__ offs, const int2* __restrict__ se,
    const float* __restrict__ eattr,
    const float* __restrict__ att, const float* __restrict__ We,
    const u16* __restrict__ xlb, const u16* __restrict__ xrb,
    float* __restrict__ gat)
{
  int l = threadIdx.x & 63;
  int l16 = l & 15, quad = l >> 4;
  int wid = (blockIdx.x * blockDim.x + threadIdx.x) >> 6;
  int nw = (gridDim.x * blockDim.x) >> 6;
  int c0 = 2 * l;
  bool kz = quad >= 2;
  int kb = (quad & 1) * 8;

  // We^T A-fragments: A[row = t*16+l16 (channel)][k = quad*8+e], zero for k>=16
  s16x8 wfrag[8];
#pragma unroll
  for (int t = 0; t < 8; ++t) {
    s16x8 b;
#pragma unroll
    for (int e = 0; e < 8; ++e) {
      float v = kz ? 0.f : We[(kb + e) * 128 + t * 16 + l16];
      b[e] = (short)f2b(v);
    }
    wfrag[t] = b;
  }
  // att (f32) at this lane's eval channels {16t + 4*quad + r}
  float4 attf[8];
#pragma unroll
  for (int t = 0; t < 8; ++t) attf[t] = *(const float4*)(att + t * 16 + quad * 4);

  for (int d = wid; d < NN; d += nw) {
    int start = offs[d];
    int deg = offs[d + 1] - start;
    // xr at eval channels (bf16, expanded on use)
    ushort4 xr_u[8];
#pragma unroll
    for (int t = 0; t < 8; ++t)
      xr_u[t] = *(const ushort4*)(xrb + d * 128 + t * 16 + quad * 4);
    float mh = -1e30f, lh = 0.f, O0 = 0.f, O1 = 0.f;

    for (int base = 0; base < deg; base += 64) {
      bool act = (base + l) < deg;
      int idx = start + base + l;
      int2 sev = act ? se[idx] : make_int2(0, 0);
      int cnt = min(64, deg - base);
      for (int sub16 = 0; sub16 < cnt; sub16 += 16) {
        int vcnt = min(16, cnt - sub16);
        int eid_b = __shfl(sev.y, sub16 + l16);   // my edge's eid (lanes >= vcnt: safe 0)
        int src_b = __shfl(sev.x, sub16 + l16);   // my edge's src row

        // B-fragment: ea^T[k][edge=l16]; quads>=2 multiplied by A-side zeros
        s16x8 eaf = ld_bf16x8_f32(eattr + (size_t)eid_b * 16 + kb);

        // ep fragments: C[ch][edge]
        f32x4v ep[8];
#pragma unroll
        for (int t = 0; t < 8; ++t)
          ep[t] = mfma16(wfrag[t], eaf, (f32x4v){0.f, 0.f, 0.f, 0.f});

        // xl of my edge at my eval channels
        ushort4 xl_u[8];
#pragma unroll
        for (int t = 0; t < 8; ++t)
          xl_u[t] = *(const ushort4*)(xlb + (size_t)src_b * 128 + t * 16 + quad * 4);

        // channel evals -> per-head partials (head of channel = t>>1)
        float ph[4] = {0.f, 0.f, 0.f, 0.f};
#pragma unroll
        for (int t = 0; t < 8; ++t) {
          int h = t >> 1;
          float4 av = attf[t];
          float m0 = ep[t][0] + b2f(xr_u[t].x) + b2f(xl_u[t].x);
          float m1 = ep[t][1] + b2f(xr_u[t].y) + b2f(xl_u[t].y);
          float m2 = ep[t][2] + b2f(xr_u[t].z) + b2f(xl_u[t].z);
          float m3 = ep[t][3] + b2f(xr_u[t].w) + b2f(xl_u[t].w);
          float s0 = fmaxf(m0, 0.2f * m0);
          float s1 = fmaxf(m1, 0.2f * m1);
          float s2 = fmaxf(m2, 0.2f * m2);
          float s3 = fmaxf(m3, 0.2f * m3);
          ph[h] = fmaf(s0, av.x, ph[h]);
          ph[h] = fmaf(s1, av.y, ph[h]);
          ph[h] = fmaf(s2, av.z, ph[h]);
          ph[h] = fmaf(s3, av.w, ph[h]);
        }
        // cross-quad select-exchange reduce: lane ends with logit[edge=l16, head=quad]
        bool q0 = (quad & 1) != 0, q1 = (quad & 2) != 0;
        float S0 = q0 ? ph[0] : ph[1];
        float S1 = q0 ? ph[2] : ph[3];
        float R0 = __shfl_xor(S0, 16);
        float R1 = __shfl_xor(S1, 16);
        float Q0 = (q0 ? ph[1] : ph[0]) + R0;   // head bit0 = quad&1, bit1 = 0
        float Q1 = (q0 ? ph[3] : ph[2]) + R1;   // bit1 = 1
        float S2 = q1 ? Q0 : Q1;
        float R2 = __shfl_xor(S2, 32);
        float lg = (q1 ? Q1 : Q0) + R2;         // logit[edge=l16, head=quad]
        if (l16 >= vcnt) lg = -1e30f;

        // block softmax over the 16 edges (per head = per quad-group lane state)
        float bm = lg;
#pragma unroll
        for (int o = 1; o <= 8; o <<= 1) bm = fmaxf(bm, __shfl_xor(bm, o));
        float nm = fmaxf(mh, bm);
        float sc = __expf(mh - nm);
        float w = __expf(lg - nm);              // my edge's weight for head=quad
        float bs = w;
#pragma unroll
        for (int o = 1; o <= 8; o <<= 1) bs += __shfl_xor(bs, o);
        lh = fmaf(lh, sc, bs);
        O0 *= sc; O1 *= sc;
        mh = nm;

        // O accumulation: lane's channels c0,c0+1 (head=quad), weights from lane (quad,e)
        int lbase = l & 48;
        for (int e = 0; e < vcnt; ++e) {
          float we = __shfl(w, lbase + e);
          int sr = readlane_i32(sev.x, sub16 + e);
          ushort2 xlu = *(const ushort2*)(xlb + (size_t)sr * 128 + c0);
          O0 = fmaf(we, b2f(xlu.x), O0);
          O1 = fmaf(we, b2f(xlu.y), O1);
        }
      }
    }
    float inv = 1.f / (lh + 1e-16f);
    *(float2*)(gat + d * 128 + c0) = make_float2(O0 * inv, O1 * inv);
  }
}

// ---------------- K5: h = rmsnorm(x + gat + bias_gat, w_norm1); also emit bf16 copy ----------------
__global__ __launch_bounds__(256) void k5_norm1(const float* __restrict__ x,
    const float* __restrict__ gat, const float* __restrict__ bg,
    const float* __restrict__ wn1, float* __restrict__ h, u16* __restrict__ hb)
{
  int l = threadIdx.x & 63;
  int row = blockIdx.x * 4 + (threadIdx.x >> 6);
  int c0 = 2 * l;
  float2 xu = *(const float2*)(x + row * 128 + c0);
  float2 gv = *(const float2*)(gat + row * 128 + c0);
  float2 bu = *(const float2*)(bg + c0);
  float v0 = xu.x + gv.x + bu.x;
  float v1 = xu.y + gv.y + bu.y;
  float ss = v0 * v0 + v1 * v1;
#pragma unroll
  for (int o = 1; o < 64; o <<= 1) ss += __shfl_xor(ss, o);
  float rr = rsqrtf(ss * (1.f / 128.f) + RMS_EPS);
  float2 wu = *(const float2*)(wn1 + c0);
  float o0 = v0 * rr * wu.x, o1 = v1 * rr * wu.y;
  *(float2*)(h + row * 128 + c0) = make_float2(o0, o1);
  ushort2 hu; hu.x = f2b(o0); hu.y = f2b(o1);
  *(ushort2*)(hb + row * 128 + c0) = hu;
}

// ---------------- K6: fused FFN (bf16 MFMA) + residual + rmsnorm2 ----------------
__device__ __forceinline__ u16* tls_addr(u16* tls, int row, int col) {
  int byte = (row << 10) + (col << 1);
  byte ^= (row & 7) << 4;
  return (u16*)((char*)tls + byte);
}

__global__ __launch_bounds__(512) void k6_mfma(const float* __restrict__ h,
    const u16* __restrict__ hb,
    const u16* __restrict__ w1t, const u16* __restrict__ w2t,
    const float* __restrict__ b1, const float* __restrict__ b2,
    const float* __restrict__ wn2, float* __restrict__ out)
{
  __shared__ u16 tls[32 * 512];
  int tid = threadIdx.x;
  int w = tid >> 6, lane = tid & 63;
  int quad = lane >> 4, l16 = lane & 15;
  int row0 = blockIdx.x * 32;
  int ko = quad * 8;

  f32x4v acc1[2][4];
#pragma unroll
  for (int mt = 0; mt < 2; ++mt)
#pragma unroll
    for (int nt = 0; nt < 4; ++nt) acc1[mt][nt] = (f32x4v){0.f, 0.f, 0.f, 0.f};
#pragma unroll
  for (int ks = 0; ks < 4; ++ks) {
    int k0 = ks * 32 + ko;
    s16x8 a[2];
#pragma unroll
    for (int mt = 0; mt < 2; ++mt) {
      int row = row0 + mt * 16 + l16; if (row >= NN) row = NN - 1;
      a[mt] = *(const s16x8*)(hb + row * 128 + k0);
    }
#pragma unroll
    for (int nt = 0; nt < 4; ++nt) {
      int col = w * 64 + nt * 16 + l16;
      s16x8 b = *(const s16x8*)(w1t + col * 128 + k0);
      acc1[0][nt] = mfma16(a[0], b, acc1[0][nt]);
      acc1[1][nt] = mfma16(a[1], b, acc1[1][nt]);
    }
  }
#pragma unroll
  for (int nt = 0; nt < 4; ++nt) {
    int col = w * 64 + nt * 16 + l16;
    float bb = b1[col];
#pragma unroll
    for (int mt = 0; mt < 2; ++mt)
#pragma unroll
      for (int r = 0; r < 4; ++r) {
        float t = gelu_fast(acc1[mt][nt][r] + bb);
        *tls_addr(tls, mt * 16 + quad * 4 + r, col) = f2b(t);
      }
  }
  __syncthreads();

  f32x4v acc2[2];
  acc2[0] = (f32x4v){0.f, 0.f, 0.f, 0.f};
  acc2[1] = (f32x4v){0.f, 0.f, 0.f, 0.f};
  int col = w * 16 + l16;
  const u16* bptr = w2t + col * 512;
#pragma unroll
  for (int ks = 0; ks < 16; ++ks) {
    int k0 = ks * 32 + ko;
    s16x8 a2[2];
#pragma unroll
    for (int mt = 0; mt < 2; ++mt)
      a2[mt] = *(const s16x8*)tls_addr(tls, mt * 16 + l16, k0);
    s16x8 b = *(const s16x8*)(bptr + k0);
    acc2[0] = mfma16(a2[0], b, acc2[0]);
    acc2[1] = mfma16(a2[1], b, acc2[1]);
  }

  float bb2 = b2[col], wn = wn2[col];
  float ov[2][4];
#pragma unroll
  for (int mt = 0; mt < 2; ++mt)
#pragma unroll
    for (int r = 0; r < 4; ++r) {
      int row = row0 + mt * 16 + quad * 4 + r;
      int rowc = row < NN ? row : NN - 1;
      ov[mt][r] = h[rowc * 128 + col] + acc2[mt][r] + bb2;
    }
  __syncthreads();
  float (*red)[32] = (float (*)[32])(void*)tls;
#pragma unroll
  for (int mt = 0; mt < 2; ++mt)
#pragma unroll
    for (int r = 0; r < 4; ++r) {
      float q = ov[mt][r] * ov[mt][r];
      q += __shfl_xor(q, 1); q += __shfl_xor(q, 2);
      q += __shfl_xor(q, 4); q += __shfl_xor(q, 8);
      if (l16 == 0) red[w][mt * 16 + quad * 4 + r] = q;
    }
  __syncthreads();
#pragma unroll
  for (int mt = 0; mt < 2; ++mt)
#pragma unroll
    for (int r = 0; r < 4; ++r) {
      int rl = mt * 16 + quad * 4 + r;
      float tot = ((red[0][rl] + red[1][rl]) + (red[2][rl] + red[3][rl]))
                + ((red[4][rl] + red[5][rl]) + (red[6][rl] + red[7][rl]));
      float rr = rsqrtf(tot * (1.f / 128.f) + RMS_EPS);
      int row = row0 + rl;
      if (row < NN) {
        out[row * 128 + col] = ov[mt][r] * rr * wn;
      }
    }
}

// ---------------- launch ----------------
extern "C" void kernel_launch(void* const* d_in, const int* in_sizes, int n_in,
                              void* d_out, int out_size, void* d_ws, size_t ws_size,
                              hipStream_t stream) {
  const float* x   = (const float*)d_in[0];
  const int*   ei  = (const int*)d_in[1];
  const float* ea  = (const float*)d_in[2];
  const float* Wl  = (const float*)d_in[3];
  const float* bl  = (const float*)d_in[4];
  const float* Wr  = (const float*)d_in[5];
  const float* br  = (const float*)d_in[6];
  const float* We  = (const float*)d_in[7];
  const float* att = (const float*)d_in[8];
  const float* bg  = (const float*)d_in[9];
  const float* wn1 = (const float*)d_in[10];
  const float* wn2 = (const float*)d_in[11];
  const float* W1  = (const float*)d_in[12];
  const float* b1  = (const float*)d_in[13];
  const float* W2  = (const float*)d_in[14];
  const float* b2  = (const float*)d_in[15];

  float* wsf = (float*)d_ws;
  int*   wsi = (int*)d_ws;

  float* gat  = wsf + OFF_GAT;
  u16* xlb    = (u16*)(wsf + OFF_XLB);
  u16* xrb    = (u16*)(wsf + OFF_XRB);
  int2* se    = (int2*)(wsf + OFF_SE);
  int* cnt    = wsi + OFF_CNT;
  int* pos    = wsi + OFF_CNT;
  int* offs   = wsi + OFF_OFS;
  float* hbuf = wsf + OFF_H;
  u16* hb     = (u16*)(wsf + OFF_HB);
  u16* wlrt   = (u16*)(wsf + OFF_WLRT);
  u16* w1t    = (u16*)(wsf + OFF_W1T);
  u16* w2t    = (u16*)(wsf + OFF_W2T);

  k_prep<<<256, 256, 0, stream>>>(Wl, Wr, W1, W2, cnt, wlrt, w1t, w2t);

  k_hist<<<(EE + 255) / 256, 256, 0, stream>>>(ei, cnt);
  k_scan<<<1, 1024, 0, stream>>>(cnt, offs, pos);
  k_permute<<<(EE + 255) / 256, 256, 0, stream>>>(ei, pos, se);

  k1_mfma<<<(NN + 31) / 32, 256, 0, stream>>>(x, wlrt, bl, br, xlb, xrb);

  k2_attn<<<2048, 256, 0, stream>>>(offs, se, ea, att, We, xlb, xrb, gat);

  k5_norm1<<<NN / 4, 256, 0, stream>>>(x, gat, bg, wn1, hbuf, hb);

  k6_mfma<<<(NN + 31) / 32, 512, 0, stream>>>(hbuf, hb, w1t, w2t, b1, b2, wn2, (float*)d_out);
}

// Round 4
// 563.728 us; speedup vs baseline: 1.1011x; 1.1011x over previous
//
#include <hip/hip_runtime.h>

// ---------------- problem constants ----------------
#define NN 50000
#define EE 800000
// HID=128, EDGE_DIM=16, HEADS=4, C=32

typedef unsigned short u16;

// ---------------- ws layout (4-byte element offsets) ----------------
// Region A: logits[E][4] f32, live k2_logits -> k3_soft
#define OFF_LOG  0u          // 3,200,000 slots (0..3.2M); 3.2M..6.4M free
#define OFF_XLB  6400000u    // N*128 bf16, live k1 -> k3_soft
#define OFF_XRB  9600000u    // N*128 bf16, live k1 -> k2_logits; then hb aliases it
#define OFF_SE   12800000u   // E int2 (CSR-ordered {src, eid}), live -> k3_soft
#define OFF_CNT  14400000u   // N ints (hist; then CSR cursors)
#define OFF_OFS  14450000u   // N+1 ints, live -> k3_soft
#define OFF_HB   9600000u    // N*128 bf16, aliases XRB (dead after k2_logits)
// fp32 h lives in d_out as scratch (k3_soft writes; k6 reads same-index before final write)
#define OFF_WLRT 16000000u   // 256x128 bf16
#define OFF_W1T  16016384u   // 512x128 bf16
#define OFF_W2T  16049152u   // 128x512 bf16
// end: 16,081,920 f32 = 64,327,680 bytes (< proven 67.9 MB budget)

#define RMS_EPS 1.1920928955078125e-7f

typedef float f32x4v __attribute__((ext_vector_type(4)));
typedef short s16x8 __attribute__((ext_vector_type(8)));

__device__ __forceinline__ f32x4v mfma16(s16x8 a, s16x8 b, f32x4v c) {
  return __builtin_amdgcn_mfma_f32_16x16x32_bf16(a, b, c, 0, 0, 0);
}
__device__ __forceinline__ u16 f2b(float f) {
  unsigned int u = __float_as_uint(f);
  unsigned int r = (u + 0x7fffu + ((u >> 16) & 1u)) >> 16;
  return (u16)r;
}
__device__ __forceinline__ float b2f(u16 u) {
  union { float f; unsigned int i; } x; x.i = ((unsigned int)u) << 16; return x.f;
}
__device__ __forceinline__ s16x8 ld_bf16x8_f32(const float* __restrict__ p) {
  float4 v0 = *(const float4*)p;
  float4 v1 = *(const float4*)(p + 4);
  s16x8 r;
  r[0] = (short)f2b(v0.x); r[1] = (short)f2b(v0.y);
  r[2] = (short)f2b(v0.z); r[3] = (short)f2b(v0.w);
  r[4] = (short)f2b(v1.x); r[5] = (short)f2b(v1.y);
  r[6] = (short)f2b(v1.z); r[7] = (short)f2b(v1.w);
  return r;
}
__device__ __forceinline__ int readlane_i32(int v, int lane) {
  return __builtin_amdgcn_readlane(v, lane);
}
// tanh-form GELU via sigmoid
__device__ __forceinline__ float gelu_fast(float x) {
  float x2 = x * x;
  float y = x * fmaf(0.07135481283f, x2, 1.5957691216f);
  float e = __expf(-y);
  return x * __builtin_amdgcn_rcpf(1.0f + e);
}

// ---------------- fused prep ----------------
__global__ __launch_bounds__(256) void k_prep(const float* __restrict__ Wl, const float* __restrict__ Wr,
    const float* __restrict__ W1, const float* __restrict__ W2,
    int* __restrict__ cnt, u16* __restrict__ wlrt, u16* __restrict__ w1t, u16* __restrict__ w2t)
{
  int i = blockIdx.x * 256 + threadIdx.x;
  if (i < NN) cnt[i] = 0;
  if (i < 32768) {
    int n = i >> 7, k = i & 127;
    float v = (n < 128) ? Wl[k * 128 + n] : Wr[k * 128 + (n - 128)];
    wlrt[i] = f2b(v);
  }
  {
    int n = i >> 7, k = i & 127;
    w1t[i] = f2b(W1[k * 512 + n]);
  }
  {
    int n = i >> 9, k = i & 511;
    w2t[i] = f2b(W2[k * 128 + n]);
  }
}

// ---------------- CSR build ----------------
__global__ __launch_bounds__(256) void k_hist(const int* __restrict__ ei, int* __restrict__ cnt) {
  int e = blockIdx.x * 256 + threadIdx.x;
  if (e < EE) atomicAdd(&cnt[ei[EE + e]], 1);
}

__global__ __launch_bounds__(1024) void k_scan(const int* __restrict__ cnt,
    int* __restrict__ offs, int* __restrict__ pos)
{
  __shared__ int wsum[16];
  __shared__ int carry_s;
  int tid = threadIdx.x, lane = tid & 63, wv = tid >> 6;
  if (tid == 0) carry_s = 0;
  __syncthreads();
  for (int base = 0; base < NN; base += 1024) {
    int i = base + tid;
    int v = (i < NN) ? cnt[i] : 0;
    int x = v;
#pragma unroll
    for (int ofs = 1; ofs < 64; ofs <<= 1) {
      int y = __shfl_up(x, ofs);
      if (lane >= ofs) x += y;
    }
    if (lane == 63) wsum[wv] = x;
    __syncthreads();
    if (wv == 0) {
      int s = (lane < 16) ? wsum[lane] : 0;
#pragma unroll
      for (int ofs = 1; ofs < 16; ofs <<= 1) {
        int y = __shfl_up(s, ofs);
        if (lane >= ofs) s += y;
      }
      if (lane < 16) wsum[lane] = s;
    }
    __syncthreads();
    int wbase = (wv > 0) ? wsum[wv - 1] : 0;
    int incl = x + wbase + carry_s;
    if (i < NN) { offs[i + 1] = incl; pos[i] = incl - v; }
    if (base == 0 && tid == 0) offs[0] = 0;
    __syncthreads();
    if (tid == 1023) carry_s = incl;
    __syncthreads();
  }
}

__global__ __launch_bounds__(256) void k_permute(const int* __restrict__ ei,
    int* __restrict__ pos, int2* __restrict__ se)
{
  int e = blockIdx.x * 256 + threadIdx.x;
  if (e < EE) {
    int slot = atomicAdd(&pos[ei[EE + e]], 1);
    se[slot] = make_int2(ei[e], e);
  }
}

// ---------------- K1: [xl|xr] = x @ [Wl|Wr] + [bl|br] -> bf16 ----------------
__global__ __launch_bounds__(256) void k1_mfma(const float* __restrict__ x, const u16* __restrict__ wlrt,
    const float* __restrict__ bl, const float* __restrict__ br,
    u16* __restrict__ xlb, u16* __restrict__ xrb)
{
  int tid = threadIdx.x;
  int w = tid >> 6, lane = tid & 63;
  int quad = lane >> 4, l16 = lane & 15;
  int row0 = blockIdx.x * 32;
  int ko = quad * 8;
  f32x4v acc[2][4];
#pragma unroll
  for (int mt = 0; mt < 2; ++mt)
#pragma unroll
    for (int nt = 0; nt < 4; ++nt) acc[mt][nt] = (f32x4v){0.f, 0.f, 0.f, 0.f};
#pragma unroll
  for (int ks = 0; ks < 4; ++ks) {
    int k0 = ks * 32 + ko;
    s16x8 a[2];
#pragma unroll
    for (int mt = 0; mt < 2; ++mt) {
      int row = row0 + mt * 16 + l16; if (row >= NN) row = NN - 1;
      a[mt] = ld_bf16x8_f32(x + row * 128 + k0);
    }
#pragma unroll
    for (int nt = 0; nt < 4; ++nt) {
      int col = w * 64 + nt * 16 + l16;
      s16x8 b = *(const s16x8*)(wlrt + col * 128 + k0);
      acc[0][nt] = mfma16(a[0], b, acc[0][nt]);
      acc[1][nt] = mfma16(a[1], b, acc[1][nt]);
    }
  }
#pragma unroll
  for (int nt = 0; nt < 4; ++nt) {
    int col = w * 64 + nt * 16 + l16;
    bool isl = col < 128;
    float bias = isl ? bl[col] : br[col - 128];
    u16* dst = isl ? xlb : xrb;
    int cc = isl ? col : col - 128;
#pragma unroll
    for (int mt = 0; mt < 2; ++mt)
#pragma unroll
      for (int r = 0; r < 4; ++r) {
        int row = row0 + mt * 16 + quad * 4 + r;
        if (row < NN) dst[row * 128 + cc] = f2b(acc[mt][nt][r] + bias);
      }
  }
}

// ---------------- K2: dense per-edge logits (original edge order, MFMA ep) ----------------
// 16 edges per wave; lane l = (quad, l16) owns edge l16 at channels {16t+4*quad+r}.
// ep = mfma(We^T-frag, ea-frag) -> C[ch][edge] (layout proven in r3).
// Cross-quad select-exchange leaves logit[edge=l16, head=quad]; coalesced store.
__global__ __launch_bounds__(256) void k2_logits(
    const int* __restrict__ ei, const float* __restrict__ eattr,
    const float* __restrict__ att, const float* __restrict__ We,
    const u16* __restrict__ xlb, const u16* __restrict__ xrb,
    float* __restrict__ logits)
{
  int l = threadIdx.x & 63;
  int l16 = l & 15, quad = l >> 4;
  int w = (blockIdx.x * 256 + threadIdx.x) >> 6;   // wave id: 0..49999
  int e = w * 16 + l16;                            // my edge (E % 16 == 0, no tail)
  bool kz = quad >= 2;
  int kb = (quad & 1) * 8;

  // We^T A-fragments: A[row = t*16+l16 (channel)][k = quad*8+j], zero for k>=16
  s16x8 wfrag[8];
#pragma unroll
  for (int t = 0; t < 8; ++t) {
    s16x8 b;
#pragma unroll
    for (int j = 0; j < 8; ++j) {
      float v = kz ? 0.f : We[(kb + j) * 128 + t * 16 + l16];
      b[j] = (short)f2b(v);
    }
    wfrag[t] = b;
  }

  int src = ei[e], dst = ei[EE + e];
  s16x8 eaf = ld_bf16x8_f32(eattr + (size_t)e * 16 + kb);

  const u16* xlp = xlb + (size_t)src * 128 + quad * 4;
  const u16* xrp = xrb + (size_t)dst * 128 + quad * 4;

  float ph[4] = {0.f, 0.f, 0.f, 0.f};
#pragma unroll
  for (int t = 0; t < 8; ++t) {
    f32x4v ep = mfma16(wfrag[t], eaf, (f32x4v){0.f, 0.f, 0.f, 0.f});
    ushort4 xl4 = *(const ushort4*)(xlp + t * 16);
    ushort4 xr4 = *(const ushort4*)(xrp + t * 16);
    float4 av = *(const float4*)(att + t * 16 + quad * 4);
    int h = t >> 1;
    float m0 = ep[0] + b2f(xl4.x) + b2f(xr4.x);
    float m1 = ep[1] + b2f(xl4.y) + b2f(xr4.y);
    float m2 = ep[2] + b2f(xl4.z) + b2f(xr4.z);
    float m3 = ep[3] + b2f(xl4.w) + b2f(xr4.w);
    float s0 = fmaxf(m0, 0.2f * m0);
    float s1 = fmaxf(m1, 0.2f * m1);
    float s2 = fmaxf(m2, 0.2f * m2);
    float s3 = fmaxf(m3, 0.2f * m3);
    ph[h] = fmaf(s0, av.x, ph[h]);
    ph[h] = fmaf(s1, av.y, ph[h]);
    ph[h] = fmaf(s2, av.z, ph[h]);
    ph[h] = fmaf(s3, av.w, ph[h]);
  }
  // cross-quad select-exchange: lane ends with logit[edge=l16, head=quad]
  bool q0 = (quad & 1) != 0, q1 = (quad & 2) != 0;
  float S0 = q0 ? ph[0] : ph[1];
  float S1 = q0 ? ph[2] : ph[3];
  float R0 = __shfl_xor(S0, 16);
  float R1 = __shfl_xor(S1, 16);
  float Q0 = (q0 ? ph[1] : ph[0]) + R0;
  float Q1 = (q0 ? ph[3] : ph[2]) + R1;
  float S2 = q1 ? Q0 : Q1;
  float R2 = __shfl_xor(S2, 32);
  float lg = (q1 ? Q1 : Q0) + R2;

  logits[(size_t)e * 4 + quad] = lg;
}

// ---------------- K3: per-dst block softmax + O-accum + fused norm1 ----------------
// Wave per dst (grid-stride). Per 16-edge batch: 1 logit gather, 16-lane max/sum
// trees, online update, O-accum (proven r1 path). Tail: fused rmsnorm1 (wave holds
// all 128 channels) -> h fp32 (into d_out scratch) + hb bf16.
__global__ __launch_bounds__(256) void k3_soft(
    const int* __restrict__ offs, const int2* __restrict__ se,
    const float* __restrict__ logits, const u16* __restrict__ xlb,
    const float* __restrict__ x, const float* __restrict__ bg,
    const float* __restrict__ wn1,
    float* __restrict__ h, u16* __restrict__ hb)
{
  int l = threadIdx.x & 63;
  int l16 = l & 15, quad = l >> 4;
  int wid = (blockIdx.x * blockDim.x + threadIdx.x) >> 6;
  int nw = (gridDim.x * blockDim.x) >> 6;
  int c0 = 2 * l;
  int lbase = l & 48;

  for (int d = wid; d < NN; d += nw) {
    int start = offs[d];
    int deg = offs[d + 1] - start;
    float mh = -1e30f, lh = 0.f, O0 = 0.f, O1 = 0.f;
    for (int base = 0; base < deg; base += 64) {
      bool act = (base + l) < deg;
      int idx = start + base + l;
      int2 sev = act ? se[idx] : make_int2(0, 0);
      int cnt = min(64, deg - base);
      for (int sub16 = 0; sub16 < cnt; sub16 += 16) {
        int vcnt = min(16, cnt - sub16);
        int eid_b = __shfl(sev.y, sub16 + l16);     // inactive source lanes hold 0 -> safe
        float lg = logits[(size_t)eid_b * 4 + quad];
        if (l16 >= vcnt) lg = -1e30f;
        // block max / sum over the 16 edges (within quad group)
        float bm = lg;
#pragma unroll
        for (int o = 1; o <= 8; o <<= 1) bm = fmaxf(bm, __shfl_xor(bm, o));
        float nm = fmaxf(mh, bm);
        float sc = __expf(mh - nm);
        float wgt = __expf(lg - nm);                // my edge's weight for head=quad
        float bs = wgt;
#pragma unroll
        for (int o = 1; o <= 8; o <<= 1) bs += __shfl_xor(bs, o);
        lh = fmaf(lh, sc, bs);
        O0 *= sc; O1 *= sc;
        mh = nm;
        // O accumulation: lane's channels c0,c0+1 (head=quad)
        for (int e2 = 0; e2 < vcnt; ++e2) {
          float we = __shfl(wgt, lbase + e2);
          int sr = readlane_i32(sev.x, sub16 + e2);
          ushort2 xlu = *(const ushort2*)(xlb + (size_t)sr * 128 + c0);
          O0 = fmaf(we, b2f(xlu.x), O0);
          O1 = fmaf(we, b2f(xlu.y), O1);
        }
      }
    }
    float inv = 1.f / (lh + 1e-16f);
    // fused norm1: v = x + gat + bias_gat; h = rmsnorm(v) * wn1
    float2 xu = *(const float2*)(x + (size_t)d * 128 + c0);
    float2 bu = *(const float2*)(bg + c0);
    float v0 = O0 * inv + xu.x + bu.x;
    float v1 = O1 * inv + xu.y + bu.y;
    float ss = v0 * v0 + v1 * v1;
#pragma unroll
    for (int o = 1; o < 64; o <<= 1) ss += __shfl_xor(ss, o);
    float rr = rsqrtf(ss * (1.f / 128.f) + RMS_EPS);
    float2 wu = *(const float2*)(wn1 + c0);
    float o0 = v0 * rr * wu.x, o1 = v1 * rr * wu.y;
    *(float2*)(h + (size_t)d * 128 + c0) = make_float2(o0, o1);
    ushort2 hu; hu.x = f2b(o0); hu.y = f2b(o1);
    *(ushort2*)(hb + (size_t)d * 128 + c0) = hu;
  }
}

// ---------------- K6: fused FFN (bf16 MFMA) + residual + rmsnorm2 ----------------
// NOTE: h and out both point at d_out (h written by k3_soft). Each thread reads its
// own h[row][col] before the block's out[row][col] writes (two barriers between);
// no __restrict__ on h/out since they alias.
__device__ __forceinline__ u16* tls_addr(u16* tls, int row, int col) {
  int byte = (row << 10) + (col << 1);
  byte ^= (row & 7) << 4;
  return (u16*)((char*)tls + byte);
}

__global__ __launch_bounds__(512) void k6_mfma(const float* h,
    const u16* __restrict__ hb,
    const u16* __restrict__ w1t, const u16* __restrict__ w2t,
    const float* __restrict__ b1, const float* __restrict__ b2,
    const float* __restrict__ wn2, float* out)
{
  __shared__ u16 tls[32 * 512];
  int tid = threadIdx.x;
  int w = tid >> 6, lane = tid & 63;
  int quad = lane >> 4, l16 = lane & 15;
  int row0 = blockIdx.x * 32;
  int ko = quad * 8;

  f32x4v acc1[2][4];
#pragma unroll
  for (int mt = 0; mt < 2; ++mt)
#pragma unroll
    for (int nt = 0; nt < 4; ++nt) acc1[mt][nt] = (f32x4v){0.f, 0.f, 0.f, 0.f};
#pragma unroll
  for (int ks = 0; ks < 4; ++ks) {
    int k0 = ks * 32 + ko;
    s16x8 a[2];
#pragma unroll
    for (int mt = 0; mt < 2; ++mt) {
      int row = row0 + mt * 16 + l16; if (row >= NN) row = NN - 1;
      a[mt] = *(const s16x8*)(hb + row * 128 + k0);
    }
#pragma unroll
    for (int nt = 0; nt < 4; ++nt) {
      int col = w * 64 + nt * 16 + l16;
      s16x8 b = *(const s16x8*)(w1t + col * 128 + k0);
      acc1[0][nt] = mfma16(a[0], b, acc1[0][nt]);
      acc1[1][nt] = mfma16(a[1], b, acc1[1][nt]);
    }
  }
#pragma unroll
  for (int nt = 0; nt < 4; ++nt) {
    int col = w * 64 + nt * 16 + l16;
    float bb = b1[col];
#pragma unroll
    for (int mt = 0; mt < 2; ++mt)
#pragma unroll
      for (int r = 0; r < 4; ++r) {
        float t = gelu_fast(acc1[mt][nt][r] + bb);
        *tls_addr(tls, mt * 16 + quad * 4 + r, col) = f2b(t);
      }
  }
  __syncthreads();

  f32x4v acc2[2];
  acc2[0] = (f32x4v){0.f, 0.f, 0.f, 0.f};
  acc2[1] = (f32x4v){0.f, 0.f, 0.f, 0.f};
  int col = w * 16 + l16;
  const u16* bptr = w2t + col * 512;
#pragma unroll
  for (int ks = 0; ks < 16; ++ks) {
    int k0 = ks * 32 + ko;
    s16x8 a2[2];
#pragma unroll
    for (int mt = 0; mt < 2; ++mt)
      a2[mt] = *(const s16x8*)tls_addr(tls, mt * 16 + l16, k0);
    s16x8 b = *(const s16x8*)(bptr + k0);
    acc2[0] = mfma16(a2[0], b, acc2[0]);
    acc2[1] = mfma16(a2[1], b, acc2[1]);
  }

  float bb2 = b2[col], wn = wn2[col];
  float ov[2][4];
#pragma unroll
  for (int mt = 0; mt < 2; ++mt)
#pragma unroll
    for (int r = 0; r < 4; ++r) {
      int row = row0 + mt * 16 + quad * 4 + r;
      int rowc = row < NN ? row : NN - 1;
      ov[mt][r] = h[rowc * 128 + col] + acc2[mt][r] + bb2;
    }
  __syncthreads();
  float (*red)[32] = (float (*)[32])(void*)tls;
#pragma unroll
  for (int mt = 0; mt < 2; ++mt)
#pragma unroll
    for (int r = 0; r < 4; ++r) {
      float q = ov[mt][r] * ov[mt][r];
      q += __shfl_xor(q, 1); q += __shfl_xor(q, 2);
      q += __shfl_xor(q, 4); q += __shfl_xor(q, 8);
      if (l16 == 0) red[w][mt * 16 + quad * 4 + r] = q;
    }
  __syncthreads();
#pragma unroll
  for (int mt = 0; mt < 2; ++mt)
#pragma unroll
    for (int r = 0; r < 4; ++r) {
      int rl = mt * 16 + quad * 4 + r;
      float tot = ((red[0][rl] + red[1][rl]) + (red[2][rl] + red[3][rl]))
                + ((red[4][rl] + red[5][rl]) + (red[6][rl] + red[7][rl]));
      float rr = rsqrtf(tot * (1.f / 128.f) + RMS_EPS);
      int row = row0 + rl;
      if (row < NN) {
        out[row * 128 + col] = ov[mt][r] * rr * wn;
      }
    }
}

// ---------------- launch ----------------
extern "C" void kernel_launch(void* const* d_in, const int* in_sizes, int n_in,
                              void* d_out, int out_size, void* d_ws, size_t ws_size,
                              hipStream_t stream) {
  const float* x   = (const float*)d_in[0];
  const int*   ei  = (const int*)d_in[1];
  const float* ea  = (const float*)d_in[2];
  const float* Wl  = (const float*)d_in[3];
  const float* bl  = (const float*)d_in[4];
  const float* Wr  = (const float*)d_in[5];
  const float* br  = (const float*)d_in[6];
  const float* We  = (const float*)d_in[7];
  const float* att = (const float*)d_in[8];
  const float* bg  = (const float*)d_in[9];
  const float* wn1 = (const float*)d_in[10];
  const float* wn2 = (const float*)d_in[11];
  const float* W1  = (const float*)d_in[12];
  const float* b1  = (const float*)d_in[13];
  const float* W2  = (const float*)d_in[14];
  const float* b2  = (const float*)d_in[15];

  float* wsf = (float*)d_ws;
  int*   wsi = (int*)d_ws;

  float* logits = wsf + OFF_LOG;
  u16* xlb    = (u16*)(wsf + OFF_XLB);
  u16* xrb    = (u16*)(wsf + OFF_XRB);
  int2* se    = (int2*)(wsf + OFF_SE);
  int* cnt    = wsi + OFF_CNT;
  int* pos    = wsi + OFF_CNT;
  int* offs   = wsi + OFF_OFS;
  u16* hb     = (u16*)(wsf + OFF_HB);   // aliases xrb (dead after k2_logits)
  u16* wlrt   = (u16*)(wsf + OFF_WLRT);
  u16* w1t    = (u16*)(wsf + OFF_W1T);
  u16* w2t    = (u16*)(wsf + OFF_W2T);
  float* hbuf = (float*)d_out;          // fp32 h scratch in output buffer

  k_prep<<<256, 256, 0, stream>>>(Wl, Wr, W1, W2, cnt, wlrt, w1t, w2t);

  k_hist<<<(EE + 255) / 256, 256, 0, stream>>>(ei, cnt);
  k_scan<<<1, 1024, 0, stream>>>(cnt, offs, pos);
  k_permute<<<(EE + 255) / 256, 256, 0, stream>>>(ei, pos, se);

  k1_mfma<<<(NN + 31) / 32, 256, 0, stream>>>(x, wlrt, bl, br, xlb, xrb);

  // dense per-edge logits (MFMA edge projection, original order)
  k2_logits<<<EE / 16 / 4, 256, 0, stream>>>(ei, ea, att, We, xlb, xrb, logits);

  // per-dst softmax + O-accum + fused norm1 -> h (d_out scratch) + hb (bf16)
  k3_soft<<<2048, 256, 0, stream>>>(offs, se, logits, xlb, x, bg, wn1, hbuf, hb);

  // fused FFN (MFMA) + residual + norm2
  k6_mfma<<<(NN + 31) / 32, 512, 0, stream>>>(hbuf, hb, w1t, w2t, b1, b2, wn2, (float*)d_out);
}

// Round 6
// 508.054 us; speedup vs baseline: 1.2218x; 1.1096x over previous
//
#include <hip/hip_runtime.h>

// ---------------- problem constants ----------------
#define NN 50000
#define EE 800000
// HID=128, EDGE_DIM=16, HEADS=4, C=32

typedef unsigned short u16;

// ---------------- ws layout (4-byte element offsets) ----------------
#define OFF_EAH  0u          // E*8 u32 (eattr fp16 pairs) = 6.4M slots, live k_hist -> kA
#define OFF_XLH  6400000u    // N*128 fp16 = 3.2M slots, live k1 -> kA
#define OFF_XRH  9600000u    // N*128 fp16 = 3.2M slots, live k1 -> kA
#define OFF_SE   12800000u   // E int2 (CSR-ordered {src, eid}) -> kA
#define OFF_CNT  14400000u   // N ints (hist; then CSR cursors)
#define OFF_OFS  14450000u   // N+1 ints -> kA
// fp32 h lives in d_out as scratch (kA writes; k6 reads same rows before final write)
#define OFF_WLRT 16000000u   // 256x128 bf16
#define OFF_W1T  16016384u   // 512x128 bf16
#define OFF_W2T  16049152u   // 128x512 bf16
// end: 16,081,920 f32 = 64,327,680 bytes (< proven 67.9 MB budget)

#define RMS_EPS 1.1920928955078125e-7f

typedef float f32x4v __attribute__((ext_vector_type(4)));
typedef short s16x8 __attribute__((ext_vector_type(8)));
typedef _Float16 h16x2 __attribute__((ext_vector_type(2)));   // arithmetic type
typedef __fp16   g16x2 __attribute__((ext_vector_type(2)));   // builtin ABI type

__device__ __forceinline__ f32x4v mfma16(s16x8 a, s16x8 b, f32x4v c) {
  return __builtin_amdgcn_mfma_f32_16x16x32_bf16(a, b, c, 0, 0, 0);
}
__device__ __forceinline__ u16 f2b(float f) {
  unsigned int u = __float_as_uint(f);
  unsigned int r = (u + 0x7fffu + ((u >> 16) & 1u)) >> 16;
  return (u16)r;
}
__device__ __forceinline__ u16 f2h(float f) {
  union { _Float16 h; u16 u; } x; x.h = (_Float16)f; return x.u;
}
// pack two f32 -> fp16x2 (v_cvt_pkrtz), bitcast to arithmetic type
__device__ __forceinline__ h16x2 pk(float a, float b) {
  union { g16x2 g; h16x2 h; } u; u.g = __builtin_amdgcn_cvt_pkrtz(a, b); return u.h;
}
__device__ __forceinline__ h16x2 u2h(unsigned int u) {
  union { unsigned int i; h16x2 h; } x; x.i = u; return x.h;
}
__device__ __forceinline__ unsigned int h2u(h16x2 h) {
  union { unsigned int i; h16x2 h; } x; x.h = h; return x.i;
}
// v_dot2_f32_f16 with union bitcast at the builtin boundary
__device__ __forceinline__ float fdot2(h16x2 a, h16x2 b, float c) {
  union { h16x2 h; g16x2 g; } ua, ub; ua.h = a; ub.h = b;
  return __builtin_amdgcn_fdot2(ua.g, ub.g, c, false);
}
// load 8 fp32, convert to bf16 fragment in-register
__device__ __forceinline__ s16x8 ld_bf16x8_f32(const float* p) {
  float4 v0 = *(const float4*)p;
  float4 v1 = *(const float4*)(p + 4);
  s16x8 r;
  r[0] = (short)f2b(v0.x); r[1] = (short)f2b(v0.y);
  r[2] = (short)f2b(v0.z); r[3] = (short)f2b(v0.w);
  r[4] = (short)f2b(v1.x); r[5] = (short)f2b(v1.y);
  r[6] = (short)f2b(v1.z); r[7] = (short)f2b(v1.w);
  return r;
}
__device__ __forceinline__ int readlane_i32(int v, int lane) {
  return __builtin_amdgcn_readlane(v, lane);
}
// tanh-form GELU via sigmoid
__device__ __forceinline__ float gelu_fast(float x) {
  float x2 = x * x;
  float y = x * fmaf(0.07135481283f, x2, 1.5957691216f);
  float e = __expf(-y);
  return x * __builtin_amdgcn_rcpf(1.0f + e);
}

// ---------------- fused prep: zero hist + 3 weight transposes (bf16) ----------------
__global__ __launch_bounds__(256) void k_prep(const float* __restrict__ Wl, const float* __restrict__ Wr,
    const float* __restrict__ W1, const float* __restrict__ W2,
    int* __restrict__ cnt, u16* __restrict__ wlrt, u16* __restrict__ w1t, u16* __restrict__ w2t)
{
  int i = blockIdx.x * 256 + threadIdx.x;
  if (i < NN) cnt[i] = 0;
  if (i < 32768) {
    int n = i >> 7, k = i & 127;
    float v = (n < 128) ? Wl[k * 128 + n] : Wr[k * 128 + (n - 128)];
    wlrt[i] = f2b(v);
  }
  {
    int n = i >> 7, k = i & 127;
    w1t[i] = f2b(W1[k * 512 + n]);
  }
  {
    int n = i >> 9, k = i & 511;
    w2t[i] = f2b(W2[k * 128 + n]);
  }
}

// ---------------- CSR build + eattr fp16 pack ----------------
__global__ __launch_bounds__(256) void k_hist(const int* __restrict__ ei, const float* __restrict__ eattr,
    int* __restrict__ cnt, unsigned int* __restrict__ eah)
{
  int e = blockIdx.x * 256 + threadIdx.x;
  if (e < EE) {
    atomicAdd(&cnt[ei[EE + e]], 1);
    const float4* src = (const float4*)(eattr + (size_t)e * 16);
    float4 v0 = src[0], v1 = src[1], v2 = src[2], v3 = src[3];
    uint4 o0, o1;
    o0.x = h2u(pk(v0.x, v0.y));
    o0.y = h2u(pk(v0.z, v0.w));
    o0.z = h2u(pk(v1.x, v1.y));
    o0.w = h2u(pk(v1.z, v1.w));
    o1.x = h2u(pk(v2.x, v2.y));
    o1.y = h2u(pk(v2.z, v2.w));
    o1.z = h2u(pk(v3.x, v3.y));
    o1.w = h2u(pk(v3.z, v3.w));
    uint4* dst = (uint4*)(eah + (size_t)e * 8);
    dst[0] = o0; dst[1] = o1;
  }
}

__global__ __launch_bounds__(1024) void k_scan(const int* __restrict__ cnt,
    int* __restrict__ offs, int* __restrict__ pos)
{
  __shared__ int wsum[16];
  __shared__ int carry_s;
  int tid = threadIdx.x, lane = tid & 63, wv = tid >> 6;
  if (tid == 0) carry_s = 0;
  __syncthreads();
  for (int base = 0; base < NN; base += 1024) {
    int i = base + tid;
    int v = (i < NN) ? cnt[i] : 0;
    int x = v;
#pragma unroll
    for (int ofs = 1; ofs < 64; ofs <<= 1) {
      int y = __shfl_up(x, ofs);
      if (lane >= ofs) x += y;
    }
    if (lane == 63) wsum[wv] = x;
    __syncthreads();
    if (wv == 0) {
      int s = (lane < 16) ? wsum[lane] : 0;
#pragma unroll
      for (int ofs = 1; ofs < 16; ofs <<= 1) {
        int y = __shfl_up(s, ofs);
        if (lane >= ofs) s += y;
      }
      if (lane < 16) wsum[lane] = s;
    }
    __syncthreads();
    int wbase = (wv > 0) ? wsum[wv - 1] : 0;
    int incl = x + wbase + carry_s;
    if (i < NN) { offs[i + 1] = incl; pos[i] = incl - v; }
    if (base == 0 && tid == 0) offs[0] = 0;
    __syncthreads();
    if (tid == 1023) carry_s = incl;
    __syncthreads();
  }
}

__global__ __launch_bounds__(256) void k_permute(const int* __restrict__ ei,
    int* __restrict__ pos, int2* __restrict__ se)
{
  int e = blockIdx.x * 256 + threadIdx.x;
  if (e < EE) {
    int slot = atomicAdd(&pos[ei[EE + e]], 1);
    se[slot] = make_int2(ei[e], e);
  }
}

// ---------------- K1: [xl|xr] = x @ [Wl|Wr] + [bl|br] -> fp16 ----------------
__global__ __launch_bounds__(256) void k1_mfma(const float* __restrict__ x, const u16* __restrict__ wlrt,
    const float* __restrict__ bl, const float* __restrict__ br,
    u16* __restrict__ xlh, u16* __restrict__ xrh)
{
  int tid = threadIdx.x;
  int w = tid >> 6, lane = tid & 63;
  int quad = lane >> 4, l16 = lane & 15;
  int row0 = blockIdx.x * 32;
  int ko = quad * 8;
  f32x4v acc[2][4];
#pragma unroll
  for (int mt = 0; mt < 2; ++mt)
#pragma unroll
    for (int nt = 0; nt < 4; ++nt) acc[mt][nt] = (f32x4v){0.f, 0.f, 0.f, 0.f};
#pragma unroll
  for (int ks = 0; ks < 4; ++ks) {
    int k0 = ks * 32 + ko;
    s16x8 a[2];
#pragma unroll
    for (int mt = 0; mt < 2; ++mt) {
      int row = row0 + mt * 16 + l16; if (row >= NN) row = NN - 1;
      a[mt] = ld_bf16x8_f32(x + row * 128 + k0);
    }
#pragma unroll
    for (int nt = 0; nt < 4; ++nt) {
      int col = w * 64 + nt * 16 + l16;
      s16x8 b = *(const s16x8*)(wlrt + col * 128 + k0);
      acc[0][nt] = mfma16(a[0], b, acc[0][nt]);
      acc[1][nt] = mfma16(a[1], b, acc[1][nt]);
    }
  }
#pragma unroll
  for (int nt = 0; nt < 4; ++nt) {
    int col = w * 64 + nt * 16 + l16;
    bool isl = col < 128;
    float bias = isl ? bl[col] : br[col - 128];
    u16* dst = isl ? xlh : xrh;
    int cc = isl ? col : col - 128;
#pragma unroll
    for (int mt = 0; mt < 2; ++mt)
#pragma unroll
      for (int r = 0; r < 4; ++r) {
        int row = row0 + mt * 16 + quad * 4 + r;
        if (row < NN) dst[row * 128 + cc] = f2h(acc[mt][nt][r] + bias);
      }
  }
}

// ---------------- KA: fused logits (fdot2) + online softmax + O-accum + norm1 ----------------
// Wave per dst (grid-stride), lane owns channels (2l, 2l+1). Per 8-edge batch:
//  - ea fp16 pairs broadcast via readlane (SGPR) feeding v_dot2_f32_f16 (16/edge)
//  - eval in packed fp16: m = xl+xr+ep; leaky = 0.6m+0.4|m|; logit partial via fdot2
//  - 16-lane shfl trees give each lane its head's logit -> weights are lane-local,
//    O-accum reuses the eval's xl half2 (no shfl/readlane/load in O path).
// Tail: fused rmsnorm1 -> h fp32 (d_out scratch).
__global__ __launch_bounds__(256) void kA_attn(
    const int* __restrict__ offs, const int2* __restrict__ se,
    const unsigned int* __restrict__ eah,
    const float* __restrict__ att, const float* __restrict__ We,
    const u16* __restrict__ xlh, const u16* __restrict__ xrh,
    const float* __restrict__ x, const float* __restrict__ bg,
    const float* __restrict__ wn1, float* __restrict__ h)
{
  int l = threadIdx.x & 63;
  int wid = (blockIdx.x * blockDim.x + threadIdx.x) >> 6;
  int nw = (gridDim.x * blockDim.x) >> 6;
  int c0 = 2 * l;

  // We pairs for my two channels: wefA[k] = (We[2k][c0], We[2k+1][c0]), wefB for c0+1
  h16x2 wefA[8], wefB[8];
#pragma unroll
  for (int k = 0; k < 8; ++k) {
    wefA[k] = pk(We[(2 * k) * 128 + c0], We[(2 * k + 1) * 128 + c0]);
    wefB[k] = pk(We[(2 * k) * 128 + c0 + 1], We[(2 * k + 1) * 128 + c0 + 1]);
  }
  h16x2 att2 = pk(att[c0], att[c0 + 1]);
  const h16x2 c06 = {(_Float16)0.6f, (_Float16)0.6f};
  const h16x2 c04 = {(_Float16)0.4f, (_Float16)0.4f};

  int myj = l >> 3, myk = l & 7;

  for (int d = wid; d < NN; d += nw) {
    int start = offs[d];
    int deg = offs[d + 1] - start;
    h16x2 xr2 = u2h(*(const unsigned int*)(xrh + (size_t)d * 128 + c0));
    float mh = -1e30f, lh = 0.f, O0 = 0.f, O1 = 0.f;

    for (int base = 0; base < deg; base += 64) {
      bool act = (base + l) < deg;
      int idx = start + base + l;
      int2 sev = act ? se[idx] : make_int2(0, 0);
      int cnt = min(64, deg - base);
      for (int sub8 = 0; sub8 < cnt; sub8 += 8) {
        // lane (j*8+k) holds fp16 pair k of edge sub8+j
        int eidq = __shfl(sev.y, sub8 + myj);
        unsigned int eav = eah[(size_t)eidq * 8 + myk];

        float p[8];
        unsigned int xlu[8];
#pragma unroll
        for (int j = 0; j < 8; ++j) {
          float ep0 = 0.f, ep1 = 0.f;
#pragma unroll
          for (int k = 0; k < 8; ++k) {
            unsigned int ev = (unsigned int)readlane_i32((int)eav, j * 8 + k);
            h16x2 e2 = u2h(ev);
            ep0 = fdot2(e2, wefA[k], ep0);
            ep1 = fdot2(e2, wefB[k], ep1);
          }
          int sr = readlane_i32(sev.x, sub8 + j);   // inactive lanes hold 0 -> safe row
          unsigned int xv = *(const unsigned int*)(xlh + (size_t)sr * 128 + c0);
          xlu[j] = xv;
          h16x2 m2 = u2h(xv) + xr2 + pk(ep0, ep1);
          h16x2 am = u2h(h2u(m2) & 0x7FFF7FFFu);
          h16x2 s2 = m2 * c06 + am * c04;          // LeakyReLU(0.2)
          p[j] = fdot2(s2, att2, 0.f);
        }
        // 16-lane head-group reduction trees (8 interleaved for ILP)
#pragma unroll
        for (int o = 1; o <= 8; o <<= 1) {
          p[0] += __shfl_xor(p[0], o); p[1] += __shfl_xor(p[1], o);
          p[2] += __shfl_xor(p[2], o); p[3] += __shfl_xor(p[3], o);
          p[4] += __shfl_xor(p[4], o); p[5] += __shfl_xor(p[5], o);
          p[6] += __shfl_xor(p[6], o); p[7] += __shfl_xor(p[7], o);
        }
        // mask tail edges AFTER reduction
#pragma unroll
        for (int j = 0; j < 8; ++j) if (sub8 + j >= cnt) p[j] = -1e30f;
        // batched online update for 8 edges
        float nm = fmaxf(fmaxf(fmaxf(p[0], p[1]), fmaxf(p[2], p[3])),
                         fmaxf(fmaxf(p[4], p[5]), fmaxf(p[6], p[7])));
        nm = fmaxf(nm, mh);
        float sc = __expf(mh - nm);
#pragma unroll
        for (int j = 0; j < 8; ++j) p[j] = __expf(p[j] - nm);
        float bs = ((p[0] + p[1]) + (p[2] + p[3])) + ((p[4] + p[5]) + (p[6] + p[7]));
        lh = fmaf(lh, sc, bs);
        O0 *= sc; O1 *= sc;
        mh = nm;
        // O accumulation: weight p[j] is already lane-local (head-replicated)
#pragma unroll
        for (int j = 0; j < 8; ++j) {
          h16x2 xl2 = u2h(xlu[j]);
          O0 = fmaf(p[j], (float)xl2.x, O0);
          O1 = fmaf(p[j], (float)xl2.y, O1);
        }
      }
    }
    float inv = 1.f / (lh + 1e-16f);
    // fused norm1: v = x + gat + bias_gat; h = rmsnorm(v) * wn1
    float2 xu = *(const float2*)(x + (size_t)d * 128 + c0);
    float2 bu = *(const float2*)(bg + c0);
    float v0 = O0 * inv + xu.x + bu.x;
    float v1 = O1 * inv + xu.y + bu.y;
    float ss = v0 * v0 + v1 * v1;
#pragma unroll
    for (int o = 1; o < 64; o <<= 1) ss += __shfl_xor(ss, o);
    float rr = rsqrtf(ss * (1.f / 128.f) + RMS_EPS);
    float2 wu = *(const float2*)(wn1 + c0);
    *(float2*)(h + (size_t)d * 128 + c0) = make_float2(v0 * rr * wu.x, v1 * rr * wu.y);
  }
}

// ---------------- K6: fused FFN (bf16 MFMA) + residual + rmsnorm2 ----------------
// h and out both point at d_out (h written by kA). Block reads only its own rows'
// h before its final out writes (barriers between); no __restrict__ on h/out.
__device__ __forceinline__ u16* tls_addr(u16* tls, int row, int col) {
  int byte = (row << 10) + (col << 1);
  byte ^= (row & 7) << 4;
  return (u16*)((char*)tls + byte);
}

__global__ __launch_bounds__(512) void k6_mfma(const float* h,
    const u16* __restrict__ w1t, const u16* __restrict__ w2t,
    const float* __restrict__ b1, const float* __restrict__ b2,
    const float* __restrict__ wn2, float* out)
{
  __shared__ u16 tls[32 * 512];
  int tid = threadIdx.x;
  int w = tid >> 6, lane = tid & 63;
  int quad = lane >> 4, l16 = lane & 15;
  int row0 = blockIdx.x * 32;
  int ko = quad * 8;

  f32x4v acc1[2][4];
#pragma unroll
  for (int mt = 0; mt < 2; ++mt)
#pragma unroll
    for (int nt = 0; nt < 4; ++nt) acc1[mt][nt] = (f32x4v){0.f, 0.f, 0.f, 0.f};
#pragma unroll
  for (int ks = 0; ks < 4; ++ks) {
    int k0 = ks * 32 + ko;
    s16x8 a[2];
#pragma unroll
    for (int mt = 0; mt < 2; ++mt) {
      int row = row0 + mt * 16 + l16; if (row >= NN) row = NN - 1;
      a[mt] = ld_bf16x8_f32(h + row * 128 + k0);
    }
#pragma unroll
    for (int nt = 0; nt < 4; ++nt) {
      int col = w * 64 + nt * 16 + l16;
      s16x8 b = *(const s16x8*)(w1t + col * 128 + k0);
      acc1[0][nt] = mfma16(a[0], b, acc1[0][nt]);
      acc1[1][nt] = mfma16(a[1], b, acc1[1][nt]);
    }
  }
#pragma unroll
  for (int nt = 0; nt < 4; ++nt) {
    int col = w * 64 + nt * 16 + l16;
    float bb = b1[col];
#pragma unroll
    for (int mt = 0; mt < 2; ++mt)
#pragma unroll
      for (int r = 0; r < 4; ++r) {
        float t = gelu_fast(acc1[mt][nt][r] + bb);
        *tls_addr(tls, mt * 16 + quad * 4 + r, col) = f2b(t);
      }
  }
  __syncthreads();

  f32x4v acc2[2];
  acc2[0] = (f32x4v){0.f, 0.f, 0.f, 0.f};
  acc2[1] = (f32x4v){0.f, 0.f, 0.f, 0.f};
  int col = w * 16 + l16;
  const u16* bptr = w2t + col * 512;
#pragma unroll
  for (int ks = 0; ks < 16; ++ks) {
    int k0 = ks * 32 + ko;
    s16x8 a2[2];
#pragma unroll
    for (int mt = 0; mt < 2; ++mt)
      a2[mt] = *(const s16x8*)tls_addr(tls, mt * 16 + l16, k0);
    s16x8 b = *(const s16x8*)(bptr + k0);
    acc2[0] = mfma16(a2[0], b, acc2[0]);
    acc2[1] = mfma16(a2[1], b, acc2[1]);
  }

  float bb2 = b2[col], wn = wn2[col];
  float ov[2][4];
#pragma unroll
  for (int mt = 0; mt < 2; ++mt)
#pragma unroll
    for (int r = 0; r < 4; ++r) {
      int row = row0 + mt * 16 + quad * 4 + r;
      int rowc = row < NN ? row : NN - 1;
      ov[mt][r] = h[rowc * 128 + col] + acc2[mt][r] + bb2;
    }
  __syncthreads();
  float (*red)[32] = (float (*)[32])(void*)tls;
#pragma unroll
  for (int mt = 0; mt < 2; ++mt)
#pragma unroll
    for (int r = 0; r < 4; ++r) {
      float q = ov[mt][r] * ov[mt][r];
      q += __shfl_xor(q, 1); q += __shfl_xor(q, 2);
      q += __shfl_xor(q, 4); q += __shfl_xor(q, 8);
      if (l16 == 0) red[w][mt * 16 + quad * 4 + r] = q;
    }
  __syncthreads();
#pragma unroll
  for (int mt = 0; mt < 2; ++mt)
#pragma unroll
    for (int r = 0; r < 4; ++r) {
      int rl = mt * 16 + quad * 4 + r;
      float tot = ((red[0][rl] + red[1][rl]) + (red[2][rl] + red[3][rl]))
                + ((red[4][rl] + red[5][rl]) + (red[6][rl] + red[7][rl]));
      float rr = rsqrtf(tot * (1.f / 128.f) + RMS_EPS);
      int row = row0 + rl;
      if (row < NN) {
        out[row * 128 + col] = ov[mt][r] * rr * wn;
      }
    }
}

// ---------------- launch ----------------
extern "C" void kernel_launch(void* const* d_in, const int* in_sizes, int n_in,
                              void* d_out, int out_size, void* d_ws, size_t ws_size,
                              hipStream_t stream) {
  const float* x   = (const float*)d_in[0];
  const int*   ei  = (const int*)d_in[1];
  const float* ea  = (const float*)d_in[2];
  const float* Wl  = (const float*)d_in[3];
  const float* bl  = (const float*)d_in[4];
  const float* Wr  = (const float*)d_in[5];
  const float* br  = (const float*)d_in[6];
  const float* We  = (const float*)d_in[7];
  const float* att = (const float*)d_in[8];
  const float* bg  = (const float*)d_in[9];
  const float* wn1 = (const float*)d_in[10];
  const float* wn2 = (const float*)d_in[11];
  const float* W1  = (const float*)d_in[12];
  const float* b1  = (const float*)d_in[13];
  const float* W2  = (const float*)d_in[14];
  const float* b2  = (const float*)d_in[15];

  float* wsf = (float*)d_ws;
  int*   wsi = (int*)d_ws;

  unsigned int* eah = (unsigned int*)(wsf + OFF_EAH);
  u16* xlh    = (u16*)(wsf + OFF_XLH);
  u16* xrh    = (u16*)(wsf + OFF_XRH);
  int2* se    = (int2*)(wsf + OFF_SE);
  int* cnt    = wsi + OFF_CNT;
  int* pos    = wsi + OFF_CNT;
  int* offs   = wsi + OFF_OFS;
  u16* wlrt   = (u16*)(wsf + OFF_WLRT);
  u16* w1t    = (u16*)(wsf + OFF_W1T);
  u16* w2t    = (u16*)(wsf + OFF_W2T);
  float* hbuf = (float*)d_out;          // fp32 h scratch in output buffer

  k_prep<<<256, 256, 0, stream>>>(Wl, Wr, W1, W2, cnt, wlrt, w1t, w2t);

  k_hist<<<(EE + 255) / 256, 256, 0, stream>>>(ei, ea, cnt, eah);
  k_scan<<<1, 1024, 0, stream>>>(cnt, offs, pos);
  k_permute<<<(EE + 255) / 256, 256, 0, stream>>>(ei, pos, se);

  k1_mfma<<<(NN + 31) / 32, 256, 0, stream>>>(x, wlrt, bl, br, xlh, xrh);

  // fused logits + softmax + O-accum + norm1
  kA_attn<<<2048, 256, 0, stream>>>(offs, se, eah, att, We, xlh, xrh, x, bg, wn1, hbuf);

  // fused FFN (MFMA) + residual + norm2
  k6_mfma<<<(NN + 31) / 32, 512, 0, stream>>>(hbuf, w1t, w2t, b1, b2, wn2, (float*)d_out);
}